// Round 18
// baseline (952.507 us; speedup 1.0000x reference)
//
#include <hip/hip_runtime.h>
#include <math.h>

#define BB 2
#define SS 1024
#define HH 768
#define NHEAD 12
#define HDIM 64
#define NLAYER 4
#define VV 32000
#define MROWS (BB*SS)

typedef unsigned short u16;
typedef __attribute__((ext_vector_type(8))) short short8;
typedef __attribute__((ext_vector_type(4))) float f32x4;
typedef __attribute__((ext_vector_type(4))) unsigned short u16x4;

__device__ __forceinline__ u16 f2bf(float f) {
    union { float f; unsigned u; } x; x.f = f;
    unsigned r = (x.u + 0x7fff + ((x.u >> 16) & 1)) >> 16;
    return (u16)r;
}
__device__ __forceinline__ float bf2f(u16 b) {
    union { unsigned u; float f; } x; x.u = ((unsigned)b) << 16;
    return x.f;
}

__device__ __forceinline__ void gload_lds16(const u16* g, u16* l) {
    __builtin_amdgcn_global_load_lds((const __attribute__((address_space(1))) void*)g,
                                     (__attribute__((address_space(3))) void*)l, 16, 0, 0);
}

// ---------------- merged weight convert+transpose + embedding --------------
// Blocks [0,51648): weight tiles; [51648, 53696): embedding rows.
__global__ __launch_bounds__(256) void conv_all(
    const float* __restrict__ qkv_w, u16* __restrict__ qkvT,
    const float* __restrict__ res_w, u16* __restrict__ resT,
    const float* __restrict__ ff1_w, u16* __restrict__ ff1T,
    const float* __restrict__ ff2_w, u16* __restrict__ ff2T,
    const float* __restrict__ pred_w, u16* __restrict__ predT,
    const int* __restrict__ ids, const float* __restrict__ bpe,
    const float* __restrict__ pos, float* __restrict__ h, u16* __restrict__ hb) {
    int id = blockIdx.x;
    if (id >= 51648) {                      // ---- embedding path ----
        int row = id - 51648;
        int t = threadIdx.x;
        if (t < 192) {
            int s = row % SS;
            int tok = ids[row];
            const float4* br = (const float4*)(bpe + (size_t)tok * HH);
            const float4* pr = (const float4*)(pos + (size_t)s * HH);
            float4 a = br[t], c = pr[t];
            a.x += c.x; a.y += c.y; a.z += c.z; a.w += c.w;
            ((float4*)(h + (size_t)row * HH))[t] = a;
            u16x4 u; u[0] = f2bf(a.x); u[1] = f2bf(a.y); u[2] = f2bf(a.z); u[3] = f2bf(a.w);
            ((u16x4*)(hb + (size_t)row * HH))[t] = u;
        }
        return;
    }
    const float* W; u16* Wt; int K, N, rem;
    if (id < 6912) {
        int l = id / 1728; rem = id - l * 1728;
        W = qkv_w + (size_t)l * HH * 3 * HH; Wt = qkvT + (size_t)l * HH * 3 * HH;
        K = HH; N = 3 * HH;
    } else if (id < 9216) {
        id -= 6912; int l = id / 576; rem = id - l * 576;
        W = res_w + (size_t)l * HH * HH; Wt = resT + (size_t)l * HH * HH;
        K = HH; N = HH;
    } else if (id < 18432) {
        id -= 9216; int l = id / 2304; rem = id - l * 2304;
        W = ff1_w + (size_t)l * HH * 4 * HH; Wt = ff1T + (size_t)l * HH * 4 * HH;
        K = HH; N = 4 * HH;
    } else if (id < 27648) {
        id -= 18432; int l = id / 2304; rem = id - l * 2304;
        W = ff2_w + (size_t)l * 4 * HH * HH; Wt = ff2T + (size_t)l * 4 * HH * HH;
        K = 4 * HH; N = HH;
    } else {
        rem = id - 27648;
        W = pred_w; Wt = predT; K = HH; N = VV;
    }
    const int nt = N / 32;
    const int k0 = (rem / nt) * 32, n0 = (rem % nt) * 32;

    __shared__ u16 tile[32][33];        // tile[n][k]
    int t = threadIdx.x;                // 256
    int ky = t >> 3, nx = (t & 7) * 4;
    float4 v = *(const float4*)(W + (size_t)(k0 + ky) * N + n0 + nx);
    tile[nx + 0][ky] = f2bf(v.x);
    tile[nx + 1][ky] = f2bf(v.y);
    tile[nx + 2][ky] = f2bf(v.z);
    tile[nx + 3][ky] = f2bf(v.w);
    __syncthreads();
    int nr = t >> 3, kc = (t & 7) * 4;
    u16x4 o;
    o[0] = tile[nr][kc + 0]; o[1] = tile[nr][kc + 1];
    o[2] = tile[nr][kc + 2]; o[3] = tile[nr][kc + 3];
    *(u16x4*)(Wt + (size_t)(n0 + nr) * K + k0 + kc) = o;
}

// ---------------- MFMA GEMM: C[M][N] = A[M][K](bf16) * Wt[N][K](bf16)^T ------
// R14-proven 2-phase double-buffer, counted vmcnt, T2 XOR-swizzle both-sides.
template<int BM, int THREADS, int WN, int ACT, int WF32, int WBF>
__global__ __launch_bounds__(THREADS) void mfma_gemm(
    const u16* __restrict__ A, const u16* __restrict__ Wt,
    const float* __restrict__ bias, float* __restrict__ C,
    u16* __restrict__ Cb, int M, int N, int K) {
    constexpr int WM = THREADS / 64 / WN;        // waves in M
    constexpr int MR = BM / (WM * 16);           // M frags per wave
    constexpr int NR = 128 / (WN * 16);          // N frags per wave
    constexpr int LPT = (BM * 8 + 1024) / THREADS; // loads/thread/tile
    __shared__ u16 As[2 * BM * 64];
    __shared__ u16 Bs[2 * 128 * 64];
    const int tid = threadIdx.x;
    const int lane = tid & 63;
    const int wid = tid >> 6;

    // XCD-aware bijective swizzle of flat block id
    const int nwg = gridDim.x * gridDim.y;
    int id = blockIdx.x + gridDim.x * blockIdx.y;
    int id2 = (nwg & 7) ? id : ((id & 7) * (nwg >> 3) + (id >> 3));
    const int brow = (id2 % gridDim.x) * BM;
    const int bcol = (id2 / gridDim.x) * 128;

    const int wr = (wid / WN) * (MR * 16);
    const int wc = (wid % WN) * (NR * 16);
    f32x4 acc[MR][NR] = {};

    const u16* Abase = A + (size_t)brow * K;
    const u16* Bbase = Wt + (size_t)bcol * K;
    const int lrow = lane & 15;
    const int lhi = lane >> 4;

    // stage one BK=64 tile: chunk c -> row r=c>>3, slot s=c&7; source slot s^(r&7)
    auto stage = [&](u16* Ad, u16* Bd, int kt) {
#pragma unroll
        for (int c0 = 0; c0 < BM * 8; c0 += THREADS) {
            int c = c0 + tid;
            int r = c >> 3, s = c & 7;
            gload_lds16(Abase + (size_t)r * K + kt + ((s ^ (r & 7)) * 8), Ad + c * 8);
        }
#pragma unroll
        for (int c0 = 0; c0 < 1024; c0 += THREADS) {
            int c = c0 + tid;
            int r = c >> 3, s = c & 7;
            gload_lds16(Bbase + (size_t)r * K + kt + ((s ^ (r & 7)) * 8), Bd + c * 8);
        }
    };

    const int nt = K / 64;
    stage(As, Bs, 0);
    for (int t = 0; t < nt; ++t) {
        u16* Ac = As + (t & 1) * (BM * 64);
        u16* Bc = Bs + (t & 1) * (128 * 64);
        if (t + 1 < nt) {
            stage(As + ((t + 1) & 1) * (BM * 64),
                  Bs + ((t + 1) & 1) * (128 * 64), (t + 1) * 64);
            if constexpr (LPT == 8)      asm volatile("s_waitcnt vmcnt(8)" ::: "memory");
            else if constexpr (LPT == 6) asm volatile("s_waitcnt vmcnt(6)" ::: "memory");
            else if constexpr (LPT == 5) asm volatile("s_waitcnt vmcnt(5)" ::: "memory");
            else                         asm volatile("s_waitcnt vmcnt(4)" ::: "memory");
        } else {
            asm volatile("s_waitcnt vmcnt(0)" ::: "memory");
        }
        __builtin_amdgcn_s_barrier();
        __builtin_amdgcn_sched_barrier(0);

        short8 a[MR][2], b[NR][2];
#pragma unroll
        for (int m = 0; m < MR; ++m) {
            const int R = wr + m * 16 + lrow;
            char* rp = (char*)Ac + R * 128;
#pragma unroll
            for (int kk = 0; kk < 2; ++kk)
                a[m][kk] = *(const short8*)(rp + (((kk * 4 + lhi) ^ (R & 7)) * 16));
        }
#pragma unroll
        for (int n = 0; n < NR; ++n) {
            const int R = wc + n * 16 + lrow;
            char* rp = (char*)Bc + R * 128;
#pragma unroll
            for (int kk = 0; kk < 2; ++kk)
                b[n][kk] = *(const short8*)(rp + (((kk * 4 + lhi) ^ (R & 7)) * 16));
        }
        __builtin_amdgcn_s_setprio(1);
#pragma unroll
        for (int kk = 0; kk < 2; ++kk)
#pragma unroll
            for (int m = 0; m < MR; ++m)
#pragma unroll
                for (int n = 0; n < NR; ++n)
                    acc[m][n] = __builtin_amdgcn_mfma_f32_16x16x32_bf16(a[m][kk], b[n][kk], acc[m][n], 0, 0, 0);
        __builtin_amdgcn_s_setprio(0);

        __builtin_amdgcn_sched_barrier(0);
        __builtin_amdgcn_s_barrier();
    }

    const int lr4 = (lane >> 4) * 4;
#pragma unroll
    for (int n = 0; n < NR; ++n) {
        int col = bcol + wc + n * 16 + lrow;
        float bv = bias ? bias[col] : 0.f;
#pragma unroll
        for (int m = 0; m < MR; ++m) {
#pragma unroll
            for (int j = 0; j < 4; ++j) {
                int row = brow + wr + m * 16 + lr4 + j;
                float v = acc[m][n][j] + bv;
                if (ACT == 1) v = 0.5f * v * (1.f + erff(v * 0.70710678118654752f));
                if (WF32) C[(size_t)row * N + col] = v;
                if (WBF)  Cb[(size_t)row * N + col] = f2bf(v);
            }
        }
    }
}

// ---------------- MFMA flash attention, KVBLK=128, split-KV=2 --------------
// blockIdx.x in [0,32): qb = 15-(x>>1) (heavy-first), sp = x&1.
// Split sp owns K-tiles [kbeg,kend) of the causal range. Emits UNnormalized
// partials O (f32) + (m,l); attn_combine merges via exact LSE rule.
__global__ __launch_bounds__(256) void attn_kernel(
    const u16* __restrict__ qkvb, const float* __restrict__ seq_mask,
    float* __restrict__ Opart, float2* __restrict__ ml) {
    __shared__ u16 Ks[128 * 64];   // 16 KB
    __shared__ u16 Vt[64 * 128];   // 16 KB
    __shared__ u16 Ps[64 * 128];   // 16 KB
    const int qb = (gridDim.x >> 1) - 1 - (blockIdx.x >> 1);  // heavy-first
    const int sp = blockIdx.x & 1;
    const int hd = blockIdx.y, b = blockIdx.z;
    const int t = threadIdx.x;
    const int lane = t & 63;
    const int w = t >> 6;
    const int lrow = lane & 15;
    const int lhi = lane >> 4;
    const int q0 = qb * 64;
    const size_t rs = 3 * HH;

    const int ntile = (q0 + 64 + 127) / 128;     // total causal K-tiles
    const int half = (ntile + 1) >> 1;
    const int kbeg = sp ? half : 0;
    const int kend = sp ? ntile : half;

    short8 aq[2];
    {
        const u16* qrow = qkvb + (size_t)(b * SS + q0 + w * 16 + lrow) * rs + hd * HDIM;
        aq[0] = *(const short8*)(qrow + lhi * 8);
        aq[1] = *(const short8*)(qrow + 32 + lhi * 8);
    }

    f32x4 o[4] = {};
    float m_[4] = {-INFINITY, -INFINITY, -INFINITY, -INFINITY};
    float l_[4] = {0.f, 0.f, 0.f, 0.f};

    const int kr = t >> 1;        // 0..127 staged k-row
    const int ch = t & 1;         // d-col half (32 cols)

    short8 kR[4], vR[4];
    if (kbeg < kend) {
        const u16* kbase = qkvb + (size_t)(b * SS + kbeg * 128 + kr) * rs + HH + hd * HDIM + ch * 32;
#pragma unroll
        for (int i = 0; i < 4; ++i) {
            kR[i] = *(const short8*)(kbase + i * 8);
            vR[i] = *(const short8*)(kbase + HH + i * 8);
        }
    }

    for (int kt = kbeg; kt < kend; ++kt) {
        const int k0 = kt * 128;
        __syncthreads();                       // prior round's LDS reads done
        // ---- write prefetched K/V regs to LDS (swizzled) ----
        {
            char* kp = (char*)Ks + kr * 128;
#pragma unroll
            for (int i = 0; i < 4; ++i)
                *(short8*)(kp + (((ch * 4 + i) ^ (kr & 7)) << 4)) = kR[i];
            const int vslot = kr >> 3;
            const int voff = (kr & 7) * 2;
#pragma unroll
            for (int i = 0; i < 4; ++i)
#pragma unroll
                for (int e = 0; e < 8; ++e) {
                    int d = ch * 32 + i * 8 + e;
                    *(u16*)((char*)Vt + d * 256 + ((vslot ^ (d & 15)) << 4) + voff) = (u16)vR[i][e];
                }
        }
        __syncthreads();

        // ---- issue next round's loads (overlap latency with compute) ----
        if (kt + 1 < kend) {
            const u16* kbase = qkvb + (size_t)(b * SS + k0 + 128 + kr) * rs + HH + hd * HDIM + ch * 32;
#pragma unroll
            for (int i = 0; i < 4; ++i) {
                kR[i] = *(const short8*)(kbase + i * 8);
                vR[i] = *(const short8*)(kbase + HH + i * 8);
            }
        }

        // ---- S = Q K^T : 8 col-frags ----
        f32x4 s[8] = {};
        __builtin_amdgcn_s_setprio(1);
#pragma unroll
        for (int n = 0; n < 8; ++n) {
            const int krow = n * 16 + lrow;
            char* kp = (char*)Ks + krow * 128;
#pragma unroll
            for (int c = 0; c < 2; ++c) {
                short8 bk = *(const short8*)(kp + (((c * 4 + lhi) ^ (krow & 7)) << 4));
                s[n] = __builtin_amdgcn_mfma_f32_16x16x32_bf16(aq[c], bk, s[n], 0, 0, 0);
            }
        }
        __builtin_amdgcn_s_setprio(0);

        // ---- online softmax ----
        float sm[8];
#pragma unroll
        for (int n = 0; n < 8; ++n) sm[n] = seq_mask[b * SS + k0 + n * 16 + lrow];
        const int diag = (kt == ntile - 1);
#pragma unroll
        for (int j = 0; j < 4; ++j) {
            const int qglob = q0 + w * 16 + lhi * 4 + j;
            float sv[8];
#pragma unroll
            for (int n = 0; n < 8; ++n) {
                const int kglob = k0 + n * 16 + lrow;
                float msk = (diag && kglob > qglob) ? 0.f : sm[n];
                sv[n] = s[n][j] * 0.125f + (1.f - msk) * (-1e9f);
            }
            float tm = fmaxf(fmaxf(fmaxf(sv[0], sv[1]), fmaxf(sv[2], sv[3])),
                             fmaxf(fmaxf(sv[4], sv[5]), fmaxf(sv[6], sv[7])));
            tm = fmaxf(tm, __shfl_xor(tm, 1));
            tm = fmaxf(tm, __shfl_xor(tm, 2));
            tm = fmaxf(tm, __shfl_xor(tm, 4));
            tm = fmaxf(tm, __shfl_xor(tm, 8));
            float mn = fmaxf(m_[j], tm);
            float sc = __expf(m_[j] - mn);
            float ps = 0.f;
#pragma unroll
            for (int n = 0; n < 8; ++n) {
                float p = __expf(sv[n] - mn);
                s[n][j] = p;
                ps += p;
            }
            ps += __shfl_xor(ps, 1);
            ps += __shfl_xor(ps, 2);
            ps += __shfl_xor(ps, 4);
            ps += __shfl_xor(ps, 8);
            l_[j] = l_[j] * sc + ps;
            m_[j] = mn;
#pragma unroll
            for (int dn = 0; dn < 4; ++dn) o[dn][j] *= sc;
        }

        // ---- P -> LDS (bf16, swizzled); wave-local strip ----
#pragma unroll
        for (int j = 0; j < 4; ++j) {
            const int prow = w * 16 + lhi * 4 + j;
            char* pp = (char*)Ps + prow * 256;
            const int poff = (lrow & 7) * 2;
#pragma unroll
            for (int n = 0; n < 8; ++n) {
                int slot = 2 * n + (lrow >> 3);
                *(u16*)(pp + ((slot ^ (prow & 15)) << 4) + poff) = f2bf(s[n][j]);
            }
        }

        // ---- PV: O += P * V^T (K=128) ----
        const int arow = w * 16 + lrow;
        char* ap_p = (char*)Ps + arow * 256;
        __builtin_amdgcn_s_setprio(1);
#pragma unroll
        for (int c = 0; c < 4; ++c) {
            short8 ap = *(const short8*)(ap_p + (((c * 4 + lhi) ^ (arow & 15)) << 4));
#pragma unroll
            for (int dn = 0; dn < 4; ++dn) {
                const int vrow = dn * 16 + lrow;
                short8 bv = *(const short8*)((char*)Vt + vrow * 256 +
                                             (((c * 4 + lhi) ^ (vrow & 15)) << 4));
                o[dn] = __builtin_amdgcn_mfma_f32_16x16x32_bf16(ap, bv, o[dn], 0, 0, 0);
            }
        }
        __builtin_amdgcn_s_setprio(0);
    }

    // ---- epilogue: write unnormalized partials + (m,l) ----
    float* obase = Opart + (size_t)sp * MROWS * HH;
#pragma unroll
    for (int j = 0; j < 4; ++j) {
        const int q = q0 + w * 16 + lhi * 4 + j;
        float* orow = obase + (size_t)(b * SS + q) * HH + hd * HDIM;
#pragma unroll
        for (int dn = 0; dn < 4; ++dn)
            orow[dn * 16 + lrow] = o[dn][j];
        if (lrow == 0) {
            float2 v; v.x = m_[j]; v.y = l_[j];
            ml[((size_t)sp * MROWS + b * SS + q) * NHEAD + hd] = v;
        }
    }
}

// ---------------- combine the two KV-splits (exact LSE merge) -> avb -------
__global__ __launch_bounds__(768) void attn_combine(
    const float* __restrict__ Opart, const float2* __restrict__ ml,
    u16* __restrict__ av) {
    const int row = blockIdx.x;           // 0..MROWS-1
    const int t = threadIdx.x;            // hd = t>>6, d = t&63
    const int hd = t >> 6;
    float2 a1 = ml[(size_t)row * NHEAD + hd];
    float2 a2 = ml[((size_t)MROWS + row) * NHEAD + hd];
    float m = fmaxf(a1.x, a2.x);
    float c1 = __expf(a1.x - m), c2 = __expf(a2.x - m);
    float inv = 1.f / (a1.y * c1 + a2.y * c2);
    float o1 = Opart[(size_t)row * HH + t];
    float o2 = Opart[(size_t)(MROWS + row) * HH + t];
    av[(size_t)row * HH + t] = f2bf((o1 * c1 + o2 * c2) * inv);
}

// ---------------- residual add + layernorm (wave-parallel, no barriers) ----
__global__ __launch_bounds__(256) void add_ln_kernel(
    float* __restrict__ h, u16* __restrict__ hb,
    const u16* __restrict__ ab,
    const float* __restrict__ g, const float* __restrict__ bta) {
    const int row = blockIdx.x * 4 + (threadIdx.x >> 6);
    const int lane = threadIdx.x & 63;
    const size_t base = (size_t)row * HH;

    float x[12];
    float sum = 0.f;
#pragma unroll
    for (int c = 0; c < 3; ++c) {
        const int col = lane * 4 + c * 256;
        float4 hv = *(const float4*)(h + base + col);
        u16x4 av = *(const u16x4*)(ab + base + col);
        x[c*4+0] = hv.x + bf2f(av[0]);
        x[c*4+1] = hv.y + bf2f(av[1]);
        x[c*4+2] = hv.z + bf2f(av[2]);
        x[c*4+3] = hv.w + bf2f(av[3]);
        sum += x[c*4+0] + x[c*4+1] + x[c*4+2] + x[c*4+3];
    }
#pragma unroll
    for (int off = 32; off; off >>= 1) sum += __shfl_xor(sum, off);
    const float mean = sum * (1.0f / 768.0f);

    float vs = 0.f;
#pragma unroll
    for (int e = 0; e < 12; ++e) { float d = x[e] - mean; vs += d * d; }
#pragma unroll
    for (int off = 32; off; off >>= 1) vs += __shfl_xor(vs, off);
    const float inv = 1.0f / sqrtf(vs * (1.0f / 768.0f) + 1e-5f);

#pragma unroll
    for (int c = 0; c < 3; ++c) {
        const int col = lane * 4 + c * 256;
        float4 gv = *(const float4*)(g + col);
        float4 bv = *(const float4*)(bta + col);
        float y0 = gv.x * (x[c*4+0] - mean) * inv + bv.x;
        float y1 = gv.y * (x[c*4+1] - mean) * inv + bv.y;
        float y2 = gv.z * (x[c*4+2] - mean) * inv + bv.z;
        float y3 = gv.w * (x[c*4+3] - mean) * inv + bv.w;
        float4 hv; hv.x = y0; hv.y = y1; hv.z = y2; hv.w = y3;
        *(float4*)(h + base + col) = hv;
        u16x4 u; u[0] = f2bf(y0); u[1] = f2bf(y1); u[2] = f2bf(y2); u[3] = f2bf(y3);
        *(u16x4*)(hb + base + col) = u;
    }
}

// ---------------- single-pass row softmax over V=32000 ----------------
__global__ __launch_bounds__(512) void softmax_v_kernel(
    const float* __restrict__ score, float* __restrict__ prob) {
    __shared__ u16 srow[VV];        // 64000 B
    __shared__ float red[512];
    int row = blockIdx.x;
    int t = threadIdx.x;
    const float4* sr = (const float4*)(score + (size_t)row * VV);
    float4* pr = (float4*)(prob + (size_t)row * VV);
    const int n4 = VV / 4;          // 8000

    float mx = -INFINITY;
    for (int i = t; i < n4; i += 512) {
        float4 v = sr[i];
        u16x4 u; u[0] = f2bf(v.x); u[1] = f2bf(v.y); u[2] = f2bf(v.z); u[3] = f2bf(v.w);
        *(u16x4*)(srow + i * 4) = u;
        mx = fmaxf(mx, fmaxf(fmaxf(bf2f(u[0]), bf2f(u[1])), fmaxf(bf2f(u[2]), bf2f(u[3]))));
    }
    red[t] = mx; __syncthreads();
    for (int o = 256; o; o >>= 1) { if (t < o) red[t] = fmaxf(red[t], red[t + o]); __syncthreads(); }
    mx = red[0];
    __syncthreads();

    float s = 0.f;
    for (int i = t; i < n4; i += 512) {
        u16x4 u = *(const u16x4*)(srow + i * 4);
        s += __expf(bf2f(u[0]) - mx) + __expf(bf2f(u[1]) - mx)
           + __expf(bf2f(u[2]) - mx) + __expf(bf2f(u[3]) - mx);
    }
    red[t] = s; __syncthreads();
    for (int o = 256; o; o >>= 1) { if (t < o) red[t] += red[t + o]; __syncthreads(); }
    float inv = 1.0f / red[0];

    for (int i = t; i < n4; i += 512) {
        u16x4 u = *(const u16x4*)(srow + i * 4);
        float4 o4;
        o4.x = __expf(bf2f(u[0]) - mx) * inv; o4.y = __expf(bf2f(u[1]) - mx) * inv;
        o4.z = __expf(bf2f(u[2]) - mx) * inv; o4.w = __expf(bf2f(u[3]) - mx) * inv;
        pr[i] = o4;
    }
}

extern "C" void kernel_launch(void* const* d_in, const int* in_sizes, int n_in,
                              void* d_out, int out_size, void* d_ws, size_t ws_size,
                              hipStream_t stream) {
    const int*   ids      = (const int*)d_in[0];
    const float* seq_mask = (const float*)d_in[1];
    const float* bpe      = (const float*)d_in[2];
    const float* pos      = (const float*)d_in[3];
    const float* qkv_w    = (const float*)d_in[4];
    const float* qkv_b    = (const float*)d_in[5];
    const float* res_w    = (const float*)d_in[6];
    const float* res_b    = (const float*)d_in[7];
    const float* ln1_g    = (const float*)d_in[8];
    const float* ln1_b    = (const float*)d_in[9];
    const float* ff1_w    = (const float*)d_in[10];
    const float* ff1_b    = (const float*)d_in[11];
    const float* ff2_w    = (const float*)d_in[12];
    const float* ff2_b    = (const float*)d_in[13];
    const float* ln2_g    = (const float*)d_in[14];
    const float* ln2_b    = (const float*)d_in[15];
    const float* pred_w   = (const float*)d_in[16];

    float* out_score = (float*)d_out;
    float* out_prob  = out_score + (size_t)MROWS * VV;

    // arena layout
    size_t off = 0;
    auto take = [&](size_t bytes) -> size_t {
        size_t p = off; off += (bytes + 255) & ~(size_t)255; return p;
    };
    const size_t o_qkvT = take((size_t)NLAYER * HH * 3 * HH * 2);
    const size_t o_resT = take((size_t)NLAYER * HH * HH * 2);
    const size_t o_ff1T = take((size_t)NLAYER * HH * 4 * HH * 2);
    const size_t o_ff2T = take((size_t)NLAYER * 4 * HH * HH * 2);
    const size_t o_predT = take((size_t)HH * VV * 2);
    const size_t o_h    = take((size_t)MROWS * HH * 4);
    const size_t o_ab   = take((size_t)MROWS * HH * 2);
    const size_t o_qkvb = take((size_t)MROWS * 3 * HH * 2);
    const size_t o_hb   = take((size_t)MROWS * HH * 2);
    const size_t o_avb  = take((size_t)MROWS * HH * 2);
    const size_t o_midb = take((size_t)MROWS * 4 * HH * 2);
    const size_t o_op   = take((size_t)2 * MROWS * HH * 4);
    const size_t o_ml   = take((size_t)2 * MROWS * NHEAD * 8);
    const size_t need = off;

    char* arena = (ws_size >= need) ? (char*)d_ws : (char*)out_prob;
    u16*   qkvT = (u16*)(arena + o_qkvT);
    u16*   resT = (u16*)(arena + o_resT);
    u16*   ff1T = (u16*)(arena + o_ff1T);
    u16*   ff2T = (u16*)(arena + o_ff2T);
    u16*   predT = (u16*)(arena + o_predT);
    float* h    = (float*)(arena + o_h);
    u16*   ab   = (u16*)(arena + o_ab);
    u16*   qkvb = (u16*)(arena + o_qkvb);
    u16*   hb   = (u16*)(arena + o_hb);
    u16*   avb  = (u16*)(arena + o_avb);
    u16*   midb = (u16*)(arena + o_midb);
    float* opart = (float*)(arena + o_op);
    float2* mlb  = (float2*)(arena + o_ml);

    conv_all<<<53696, 256, 0, stream>>>(qkv_w, qkvT, res_w, resT,
                                        ff1_w, ff1T, ff2_w, ff2T, pred_w, predT,
                                        ids, bpe, pos, h, hb);

    for (int l = 0; l < NLAYER; ++l) {
        mfma_gemm<64, 256, 2, 0, 0, 1><<<dim3(MROWS / 64, 3 * HH / 128), 256, 0, stream>>>(
            hb, qkvT + (size_t)l * HH * 3 * HH, qkv_b + (size_t)l * 3 * HH,
            nullptr, qkvb, MROWS, 3 * HH, HH);
        attn_kernel<<<dim3(SS / 64 * 2, NHEAD, BB), 256, 0, stream>>>(qkvb, seq_mask, opart, mlb);
        attn_combine<<<MROWS, 768, 0, stream>>>(opart, mlb, avb);
        mfma_gemm<32, 256, 2, 0, 0, 1><<<dim3(MROWS / 32, HH / 128), 256, 0, stream>>>(
            avb, resT + (size_t)l * HH * HH, res_b + (size_t)l * HH,
            nullptr, ab, MROWS, HH, HH);
        add_ln_kernel<<<MROWS / 4, 256, 0, stream>>>(h, hb, ab,
            ln1_g + (size_t)l * HH, ln1_b + (size_t)l * HH);
        mfma_gemm<64, 256, 2, 1, 0, 1><<<dim3(MROWS / 64, 4 * HH / 128), 256, 0, stream>>>(
            hb, ff1T + (size_t)l * HH * 4 * HH, ff1_b + (size_t)l * 4 * HH,
            nullptr, midb, MROWS, 4 * HH, HH);
        mfma_gemm<32, 256, 2, 0, 0, 1><<<dim3(MROWS / 32, HH / 128), 256, 0, stream>>>(
            midb, ff2T + (size_t)l * 4 * HH * HH, ff2_b + (size_t)l * HH,
            nullptr, ab, MROWS, HH, 4 * HH);
        add_ln_kernel<<<MROWS / 4, 256, 0, stream>>>(h, hb, ab,
            ln2_g + (size_t)l * HH, ln2_b + (size_t)l * HH);
    }

    mfma_gemm<128, 512, 4, 0, 1, 0><<<dim3(MROWS / 128, VV / 128), 512, 0, stream>>>(
        hb, predT, nullptr, out_score, nullptr, MROWS, VV, HH);
    softmax_v_kernel<<<MROWS, 512, 0, stream>>>(out_score, out_prob);
}

// Round 19
// 931.939 us; speedup vs baseline: 1.0221x; 1.0221x over previous
//
#include <hip/hip_runtime.h>
#include <math.h>

#define BB 2
#define SS 1024
#define HH 768
#define NHEAD 12
#define HDIM 64
#define NLAYER 4
#define VV 32000
#define MROWS (BB*SS)

typedef unsigned short u16;
typedef __attribute__((ext_vector_type(8))) short short8;
typedef __attribute__((ext_vector_type(4))) float f32x4;
typedef __attribute__((ext_vector_type(4))) unsigned short u16x4;

__device__ __forceinline__ u16 f2bf(float f) {
    union { float f; unsigned u; } x; x.f = f;
    unsigned r = (x.u + 0x7fff + ((x.u >> 16) & 1)) >> 16;
    return (u16)r;
}
__device__ __forceinline__ float bf2f(u16 b) {
    union { unsigned u; float f; } x; x.u = ((unsigned)b) << 16;
    return x.f;
}

__device__ __forceinline__ void gload_lds16(const u16* g, u16* l) {
    __builtin_amdgcn_global_load_lds((const __attribute__((address_space(1))) void*)g,
                                     (__attribute__((address_space(3))) void*)l, 16, 0, 0);
}

// ---------------- merged weight convert+transpose + embedding --------------
// Blocks [0,51648): weight tiles; [51648, 53696): embedding rows.
__global__ __launch_bounds__(256) void conv_all(
    const float* __restrict__ qkv_w, u16* __restrict__ qkvT,
    const float* __restrict__ res_w, u16* __restrict__ resT,
    const float* __restrict__ ff1_w, u16* __restrict__ ff1T,
    const float* __restrict__ ff2_w, u16* __restrict__ ff2T,
    const float* __restrict__ pred_w, u16* __restrict__ predT,
    const int* __restrict__ ids, const float* __restrict__ bpe,
    const float* __restrict__ pos, float* __restrict__ h, u16* __restrict__ hb) {
    int id = blockIdx.x;
    if (id >= 51648) {                      // ---- embedding path ----
        int row = id - 51648;
        int t = threadIdx.x;
        if (t < 192) {
            int s = row % SS;
            int tok = ids[row];
            const float4* br = (const float4*)(bpe + (size_t)tok * HH);
            const float4* pr = (const float4*)(pos + (size_t)s * HH);
            float4 a = br[t], c = pr[t];
            a.x += c.x; a.y += c.y; a.z += c.z; a.w += c.w;
            ((float4*)(h + (size_t)row * HH))[t] = a;
            u16x4 u; u[0] = f2bf(a.x); u[1] = f2bf(a.y); u[2] = f2bf(a.z); u[3] = f2bf(a.w);
            ((u16x4*)(hb + (size_t)row * HH))[t] = u;
        }
        return;
    }
    const float* W; u16* Wt; int K, N, rem;
    if (id < 6912) {
        int l = id / 1728; rem = id - l * 1728;
        W = qkv_w + (size_t)l * HH * 3 * HH; Wt = qkvT + (size_t)l * HH * 3 * HH;
        K = HH; N = 3 * HH;
    } else if (id < 9216) {
        id -= 6912; int l = id / 576; rem = id - l * 576;
        W = res_w + (size_t)l * HH * HH; Wt = resT + (size_t)l * HH * HH;
        K = HH; N = HH;
    } else if (id < 18432) {
        id -= 9216; int l = id / 2304; rem = id - l * 2304;
        W = ff1_w + (size_t)l * HH * 4 * HH; Wt = ff1T + (size_t)l * HH * 4 * HH;
        K = HH; N = 4 * HH;
    } else if (id < 27648) {
        id -= 18432; int l = id / 2304; rem = id - l * 2304;
        W = ff2_w + (size_t)l * 4 * HH * HH; Wt = ff2T + (size_t)l * 4 * HH * HH;
        K = 4 * HH; N = HH;
    } else {
        rem = id - 27648;
        W = pred_w; Wt = predT; K = HH; N = VV;
    }
    const int nt = N / 32;
    const int k0 = (rem / nt) * 32, n0 = (rem % nt) * 32;

    __shared__ u16 tile[32][33];        // tile[n][k]
    int t = threadIdx.x;                // 256
    int ky = t >> 3, nx = (t & 7) * 4;
    float4 v = *(const float4*)(W + (size_t)(k0 + ky) * N + n0 + nx);
    tile[nx + 0][ky] = f2bf(v.x);
    tile[nx + 1][ky] = f2bf(v.y);
    tile[nx + 2][ky] = f2bf(v.z);
    tile[nx + 3][ky] = f2bf(v.w);
    __syncthreads();
    int nr = t >> 3, kc = (t & 7) * 4;
    u16x4 o;
    o[0] = tile[nr][kc + 0]; o[1] = tile[nr][kc + 1];
    o[2] = tile[nr][kc + 2]; o[3] = tile[nr][kc + 3];
    *(u16x4*)(Wt + (size_t)(n0 + nr) * K + k0 + kc) = o;
}

// ---------------- MFMA GEMM: C[M][N] = A[M][K](bf16) * Wt[N][K](bf16)^T ------
// R14-proven 2-phase double-buffer, counted vmcnt, T2 XOR-swizzle both-sides.
template<int BM, int THREADS, int WN, int ACT, int WF32, int WBF>
__global__ __launch_bounds__(THREADS) void mfma_gemm(
    const u16* __restrict__ A, const u16* __restrict__ Wt,
    const float* __restrict__ bias, float* __restrict__ C,
    u16* __restrict__ Cb, int M, int N, int K) {
    constexpr int WM = THREADS / 64 / WN;        // waves in M
    constexpr int MR = BM / (WM * 16);           // M frags per wave
    constexpr int NR = 128 / (WN * 16);          // N frags per wave
    constexpr int LPT = (BM * 8 + 1024) / THREADS; // loads/thread/tile
    __shared__ u16 As[2 * BM * 64];
    __shared__ u16 Bs[2 * 128 * 64];
    const int tid = threadIdx.x;
    const int lane = tid & 63;
    const int wid = tid >> 6;

    // XCD-aware bijective swizzle of flat block id
    const int nwg = gridDim.x * gridDim.y;
    int id = blockIdx.x + gridDim.x * blockIdx.y;
    int id2 = (nwg & 7) ? id : ((id & 7) * (nwg >> 3) + (id >> 3));
    const int brow = (id2 % gridDim.x) * BM;
    const int bcol = (id2 / gridDim.x) * 128;

    const int wr = (wid / WN) * (MR * 16);
    const int wc = (wid % WN) * (NR * 16);
    f32x4 acc[MR][NR] = {};

    const u16* Abase = A + (size_t)brow * K;
    const u16* Bbase = Wt + (size_t)bcol * K;
    const int lrow = lane & 15;
    const int lhi = lane >> 4;

    // stage one BK=64 tile: chunk c -> row r=c>>3, slot s=c&7; source slot s^(r&7)
    auto stage = [&](u16* Ad, u16* Bd, int kt) {
#pragma unroll
        for (int c0 = 0; c0 < BM * 8; c0 += THREADS) {
            int c = c0 + tid;
            int r = c >> 3, s = c & 7;
            gload_lds16(Abase + (size_t)r * K + kt + ((s ^ (r & 7)) * 8), Ad + c * 8);
        }
#pragma unroll
        for (int c0 = 0; c0 < 1024; c0 += THREADS) {
            int c = c0 + tid;
            int r = c >> 3, s = c & 7;
            gload_lds16(Bbase + (size_t)r * K + kt + ((s ^ (r & 7)) * 8), Bd + c * 8);
        }
    };

    const int nt = K / 64;
    stage(As, Bs, 0);
    for (int t = 0; t < nt; ++t) {
        u16* Ac = As + (t & 1) * (BM * 64);
        u16* Bc = Bs + (t & 1) * (128 * 64);
        if (t + 1 < nt) {
            stage(As + ((t + 1) & 1) * (BM * 64),
                  Bs + ((t + 1) & 1) * (128 * 64), (t + 1) * 64);
            if constexpr (LPT == 8)      asm volatile("s_waitcnt vmcnt(8)" ::: "memory");
            else if constexpr (LPT == 6) asm volatile("s_waitcnt vmcnt(6)" ::: "memory");
            else if constexpr (LPT == 5) asm volatile("s_waitcnt vmcnt(5)" ::: "memory");
            else                         asm volatile("s_waitcnt vmcnt(4)" ::: "memory");
        } else {
            asm volatile("s_waitcnt vmcnt(0)" ::: "memory");
        }
        __builtin_amdgcn_s_barrier();
        __builtin_amdgcn_sched_barrier(0);

        short8 a[MR][2], b[NR][2];
#pragma unroll
        for (int m = 0; m < MR; ++m) {
            const int R = wr + m * 16 + lrow;
            char* rp = (char*)Ac + R * 128;
#pragma unroll
            for (int kk = 0; kk < 2; ++kk)
                a[m][kk] = *(const short8*)(rp + (((kk * 4 + lhi) ^ (R & 7)) * 16));
        }
#pragma unroll
        for (int n = 0; n < NR; ++n) {
            const int R = wc + n * 16 + lrow;
            char* rp = (char*)Bc + R * 128;
#pragma unroll
            for (int kk = 0; kk < 2; ++kk)
                b[n][kk] = *(const short8*)(rp + (((kk * 4 + lhi) ^ (R & 7)) * 16));
        }
        __builtin_amdgcn_s_setprio(1);
#pragma unroll
        for (int kk = 0; kk < 2; ++kk)
#pragma unroll
            for (int m = 0; m < MR; ++m)
#pragma unroll
                for (int n = 0; n < NR; ++n)
                    acc[m][n] = __builtin_amdgcn_mfma_f32_16x16x32_bf16(a[m][kk], b[n][kk], acc[m][n], 0, 0, 0);
        __builtin_amdgcn_s_setprio(0);

        __builtin_amdgcn_sched_barrier(0);
        __builtin_amdgcn_s_barrier();
    }

    const int lr4 = (lane >> 4) * 4;
#pragma unroll
    for (int n = 0; n < NR; ++n) {
        int col = bcol + wc + n * 16 + lrow;
        float bv = bias ? bias[col] : 0.f;
#pragma unroll
        for (int m = 0; m < MR; ++m) {
#pragma unroll
            for (int j = 0; j < 4; ++j) {
                int row = brow + wr + m * 16 + lr4 + j;
                float v = acc[m][n][j] + bv;
                if (ACT == 1) v = 0.5f * v * (1.f + erff(v * 0.70710678118654752f));
                if (WF32) C[(size_t)row * N + col] = v;
                if (WBF)  Cb[(size_t)row * N + col] = f2bf(v);
            }
        }
    }
}

// ---------------- MFMA flash attention, KVBLK=128 (R17-proven) -------------
__global__ __launch_bounds__(256) void attn_kernel(
    const u16* __restrict__ qkvb, const float* __restrict__ seq_mask,
    u16* __restrict__ av) {
    __shared__ u16 Ks[128 * 64];   // 16 KB
    __shared__ u16 Vt[64 * 128];   // 16 KB
    __shared__ u16 Ps[64 * 128];   // 16 KB
    const int qb = gridDim.x - 1 - blockIdx.x;   // heavy-first
    const int hd = blockIdx.y, b = blockIdx.z;
    const int t = threadIdx.x;
    const int lane = t & 63;
    const int w = t >> 6;
    const int lrow = lane & 15;
    const int lhi = lane >> 4;
    const int q0 = qb * 64;
    const size_t rs = 3 * HH;

    short8 aq[2];
    {
        const u16* qrow = qkvb + (size_t)(b * SS + q0 + w * 16 + lrow) * rs + hd * HDIM;
        aq[0] = *(const short8*)(qrow + lhi * 8);
        aq[1] = *(const short8*)(qrow + 32 + lhi * 8);
    }

    f32x4 o[4] = {};
    float m_[4] = {-INFINITY, -INFINITY, -INFINITY, -INFINITY};
    float l_[4] = {0.f, 0.f, 0.f, 0.f};

    const int kr = t >> 1;        // 0..127 staged k-row
    const int ch = t & 1;         // d-col half (32 cols)
    const int ntile = (q0 + 64 + 127) / 128;

    short8 kR[4], vR[4];
    {
        const u16* kbase = qkvb + (size_t)(b * SS + kr) * rs + HH + hd * HDIM + ch * 32;
#pragma unroll
        for (int i = 0; i < 4; ++i) {
            kR[i] = *(const short8*)(kbase + i * 8);
            vR[i] = *(const short8*)(kbase + HH + i * 8);
        }
    }

    for (int kt = 0; kt < ntile; ++kt) {
        const int k0 = kt * 128;
        __syncthreads();                       // prior round's LDS reads done
        // ---- write prefetched K/V regs to LDS (swizzled) ----
        {
            char* kp = (char*)Ks + kr * 128;
#pragma unroll
            for (int i = 0; i < 4; ++i)
                *(short8*)(kp + (((ch * 4 + i) ^ (kr & 7)) << 4)) = kR[i];
            const int vslot = kr >> 3;
            const int voff = (kr & 7) * 2;
#pragma unroll
            for (int i = 0; i < 4; ++i)
#pragma unroll
                for (int e = 0; e < 8; ++e) {
                    int d = ch * 32 + i * 8 + e;
                    *(u16*)((char*)Vt + d * 256 + ((vslot ^ (d & 15)) << 4) + voff) = (u16)vR[i][e];
                }
        }
        __syncthreads();

        // ---- issue next round's loads (overlap latency with compute) ----
        if (kt + 1 < ntile) {
            const u16* kbase = qkvb + (size_t)(b * SS + k0 + 128 + kr) * rs + HH + hd * HDIM + ch * 32;
#pragma unroll
            for (int i = 0; i < 4; ++i) {
                kR[i] = *(const short8*)(kbase + i * 8);
                vR[i] = *(const short8*)(kbase + HH + i * 8);
            }
        }

        // ---- S = Q K^T : 8 col-frags ----
        f32x4 s[8] = {};
        __builtin_amdgcn_s_setprio(1);
#pragma unroll
        for (int n = 0; n < 8; ++n) {
            const int krow = n * 16 + lrow;
            char* kp = (char*)Ks + krow * 128;
#pragma unroll
            for (int c = 0; c < 2; ++c) {
                short8 bk = *(const short8*)(kp + (((c * 4 + lhi) ^ (krow & 7)) << 4));
                s[n] = __builtin_amdgcn_mfma_f32_16x16x32_bf16(aq[c], bk, s[n], 0, 0, 0);
            }
        }
        __builtin_amdgcn_s_setprio(0);

        // ---- online softmax ----
        float sm[8];
#pragma unroll
        for (int n = 0; n < 8; ++n) sm[n] = seq_mask[b * SS + k0 + n * 16 + lrow];
        const int diag = (kt == ntile - 1);
#pragma unroll
        for (int j = 0; j < 4; ++j) {
            const int qglob = q0 + w * 16 + lhi * 4 + j;
            float sv[8];
#pragma unroll
            for (int n = 0; n < 8; ++n) {
                const int kglob = k0 + n * 16 + lrow;
                float msk = (diag && kglob > qglob) ? 0.f : sm[n];
                sv[n] = s[n][j] * 0.125f + (1.f - msk) * (-1e9f);
            }
            float tm = fmaxf(fmaxf(fmaxf(sv[0], sv[1]), fmaxf(sv[2], sv[3])),
                             fmaxf(fmaxf(sv[4], sv[5]), fmaxf(sv[6], sv[7])));
            tm = fmaxf(tm, __shfl_xor(tm, 1));
            tm = fmaxf(tm, __shfl_xor(tm, 2));
            tm = fmaxf(tm, __shfl_xor(tm, 4));
            tm = fmaxf(tm, __shfl_xor(tm, 8));
            float mn = fmaxf(m_[j], tm);
            float sc = __expf(m_[j] - mn);
            float ps = 0.f;
#pragma unroll
            for (int n = 0; n < 8; ++n) {
                float p = __expf(sv[n] - mn);
                s[n][j] = p;
                ps += p;
            }
            ps += __shfl_xor(ps, 1);
            ps += __shfl_xor(ps, 2);
            ps += __shfl_xor(ps, 4);
            ps += __shfl_xor(ps, 8);
            l_[j] = l_[j] * sc + ps;
            m_[j] = mn;
#pragma unroll
            for (int dn = 0; dn < 4; ++dn) o[dn][j] *= sc;
        }

        // ---- P -> LDS (bf16, swizzled); wave-local strip ----
#pragma unroll
        for (int j = 0; j < 4; ++j) {
            const int prow = w * 16 + lhi * 4 + j;
            char* pp = (char*)Ps + prow * 256;
            const int poff = (lrow & 7) * 2;
#pragma unroll
            for (int n = 0; n < 8; ++n) {
                int slot = 2 * n + (lrow >> 3);
                *(u16*)(pp + ((slot ^ (prow & 15)) << 4) + poff) = f2bf(s[n][j]);
            }
        }

        // ---- PV: O += P * V^T (K=128) ----
        const int arow = w * 16 + lrow;
        char* ap_p = (char*)Ps + arow * 256;
        __builtin_amdgcn_s_setprio(1);
#pragma unroll
        for (int c = 0; c < 4; ++c) {
            short8 ap = *(const short8*)(ap_p + (((c * 4 + lhi) ^ (arow & 15)) << 4));
#pragma unroll
            for (int dn = 0; dn < 4; ++dn) {
                const int vrow = dn * 16 + lrow;
                short8 bv = *(const short8*)((char*)Vt + vrow * 256 +
                                             (((c * 4 + lhi) ^ (vrow & 15)) << 4));
                o[dn] = __builtin_amdgcn_mfma_f32_16x16x32_bf16(ap, bv, o[dn], 0, 0, 0);
            }
        }
        __builtin_amdgcn_s_setprio(0);
    }

    // ---- epilogue: normalize + store bf16 ----
#pragma unroll
    for (int j = 0; j < 4; ++j) {
        const int q = q0 + w * 16 + lhi * 4 + j;
        const float inv = 1.f / l_[j];
        u16* orow = av + (size_t)(b * SS + q) * HH + hd * HDIM;
#pragma unroll
        for (int dn = 0; dn < 4; ++dn)
            orow[dn * 16 + lrow] = f2bf(o[dn][j] * inv);
    }
}

// ---------------- residual add + layernorm (wave-parallel, no barriers) ----
__global__ __launch_bounds__(256) void add_ln_kernel(
    float* __restrict__ h, u16* __restrict__ hb,
    const u16* __restrict__ ab,
    const float* __restrict__ g, const float* __restrict__ bta) {
    const int row = blockIdx.x * 4 + (threadIdx.x >> 6);
    const int lane = threadIdx.x & 63;
    const size_t base = (size_t)row * HH;

    float x[12];
    float sum = 0.f;
#pragma unroll
    for (int c = 0; c < 3; ++c) {
        const int col = lane * 4 + c * 256;
        float4 hv = *(const float4*)(h + base + col);
        u16x4 av = *(const u16x4*)(ab + base + col);
        x[c*4+0] = hv.x + bf2f(av[0]);
        x[c*4+1] = hv.y + bf2f(av[1]);
        x[c*4+2] = hv.z + bf2f(av[2]);
        x[c*4+3] = hv.w + bf2f(av[3]);
        sum += x[c*4+0] + x[c*4+1] + x[c*4+2] + x[c*4+3];
    }
#pragma unroll
    for (int off = 32; off; off >>= 1) sum += __shfl_xor(sum, off);
    const float mean = sum * (1.0f / 768.0f);

    float vs = 0.f;
#pragma unroll
    for (int e = 0; e < 12; ++e) { float d = x[e] - mean; vs += d * d; }
#pragma unroll
    for (int off = 32; off; off >>= 1) vs += __shfl_xor(vs, off);
    const float inv = 1.0f / sqrtf(vs * (1.0f / 768.0f) + 1e-5f);

#pragma unroll
    for (int c = 0; c < 3; ++c) {
        const int col = lane * 4 + c * 256;
        float4 gv = *(const float4*)(g + col);
        float4 bv = *(const float4*)(bta + col);
        float y0 = gv.x * (x[c*4+0] - mean) * inv + bv.x;
        float y1 = gv.y * (x[c*4+1] - mean) * inv + bv.y;
        float y2 = gv.z * (x[c*4+2] - mean) * inv + bv.z;
        float y3 = gv.w * (x[c*4+3] - mean) * inv + bv.w;
        float4 hv; hv.x = y0; hv.y = y1; hv.z = y2; hv.w = y3;
        *(float4*)(h + base + col) = hv;
        u16x4 u; u[0] = f2bf(y0); u[1] = f2bf(y1); u[2] = f2bf(y2); u[3] = f2bf(y3);
        *(u16x4*)(hb + base + col) = u;
    }
}

// ---------------- single-pass row softmax over V=32000 ----------------
__global__ __launch_bounds__(512) void softmax_v_kernel(
    const float* __restrict__ score, float* __restrict__ prob) {
    __shared__ u16 srow[VV];        // 64000 B
    __shared__ float red[512];
    int row = blockIdx.x;
    int t = threadIdx.x;
    const float4* sr = (const float4*)(score + (size_t)row * VV);
    float4* pr = (float4*)(prob + (size_t)row * VV);
    const int n4 = VV / 4;          // 8000

    float mx = -INFINITY;
    for (int i = t; i < n4; i += 512) {
        float4 v = sr[i];
        u16x4 u; u[0] = f2bf(v.x); u[1] = f2bf(v.y); u[2] = f2bf(v.z); u[3] = f2bf(v.w);
        *(u16x4*)(srow + i * 4) = u;
        mx = fmaxf(mx, fmaxf(fmaxf(bf2f(u[0]), bf2f(u[1])), fmaxf(bf2f(u[2]), bf2f(u[3]))));
    }
    red[t] = mx; __syncthreads();
    for (int o = 256; o; o >>= 1) { if (t < o) red[t] = fmaxf(red[t], red[t + o]); __syncthreads(); }
    mx = red[0];
    __syncthreads();

    float s = 0.f;
    for (int i = t; i < n4; i += 512) {
        u16x4 u = *(const u16x4*)(srow + i * 4);
        s += __expf(bf2f(u[0]) - mx) + __expf(bf2f(u[1]) - mx)
           + __expf(bf2f(u[2]) - mx) + __expf(bf2f(u[3]) - mx);
    }
    red[t] = s; __syncthreads();
    for (int o = 256; o; o >>= 1) { if (t < o) red[t] += red[t + o]; __syncthreads(); }
    float inv = 1.0f / red[0];

    for (int i = t; i < n4; i += 512) {
        u16x4 u = *(const u16x4*)(srow + i * 4);
        float4 o4;
        o4.x = __expf(bf2f(u[0]) - mx) * inv; o4.y = __expf(bf2f(u[1]) - mx) * inv;
        o4.z = __expf(bf2f(u[2]) - mx) * inv; o4.w = __expf(bf2f(u[3]) - mx) * inv;
        pr[i] = o4;
    }
}

extern "C" void kernel_launch(void* const* d_in, const int* in_sizes, int n_in,
                              void* d_out, int out_size, void* d_ws, size_t ws_size,
                              hipStream_t stream) {
    const int*   ids      = (const int*)d_in[0];
    const float* seq_mask = (const float*)d_in[1];
    const float* bpe      = (const float*)d_in[2];
    const float* pos      = (const float*)d_in[3];
    const float* qkv_w    = (const float*)d_in[4];
    const float* qkv_b    = (const float*)d_in[5];
    const float* res_w    = (const float*)d_in[6];
    const float* res_b    = (const float*)d_in[7];
    const float* ln1_g    = (const float*)d_in[8];
    const float* ln1_b    = (const float*)d_in[9];
    const float* ff1_w    = (const float*)d_in[10];
    const float* ff1_b    = (const float*)d_in[11];
    const float* ff2_w    = (const float*)d_in[12];
    const float* ff2_b    = (const float*)d_in[13];
    const float* ln2_g    = (const float*)d_in[14];
    const float* ln2_b    = (const float*)d_in[15];
    const float* pred_w   = (const float*)d_in[16];

    float* out_score = (float*)d_out;
    float* out_prob  = out_score + (size_t)MROWS * VV;

    // arena layout
    size_t off = 0;
    auto take = [&](size_t bytes) -> size_t {
        size_t p = off; off += (bytes + 255) & ~(size_t)255; return p;
    };
    const size_t o_qkvT = take((size_t)NLAYER * HH * 3 * HH * 2);
    const size_t o_resT = take((size_t)NLAYER * HH * HH * 2);
    const size_t o_ff1T = take((size_t)NLAYER * HH * 4 * HH * 2);
    const size_t o_ff2T = take((size_t)NLAYER * 4 * HH * HH * 2);
    const size_t o_predT = take((size_t)HH * VV * 2);
    const size_t o_h    = take((size_t)MROWS * HH * 4);
    const size_t o_ab   = take((size_t)MROWS * HH * 2);
    const size_t o_qkvb = take((size_t)MROWS * 3 * HH * 2);
    const size_t o_hb   = take((size_t)MROWS * HH * 2);
    const size_t o_avb  = take((size_t)MROWS * HH * 2);
    const size_t o_midb = take((size_t)MROWS * 4 * HH * 2);
    const size_t need = off;

    char* arena = (ws_size >= need) ? (char*)d_ws : (char*)out_prob;
    u16*   qkvT = (u16*)(arena + o_qkvT);
    u16*   resT = (u16*)(arena + o_resT);
    u16*   ff1T = (u16*)(arena + o_ff1T);
    u16*   ff2T = (u16*)(arena + o_ff2T);
    u16*   predT = (u16*)(arena + o_predT);
    float* h    = (float*)(arena + o_h);
    u16*   ab   = (u16*)(arena + o_ab);
    u16*   qkvb = (u16*)(arena + o_qkvb);
    u16*   hb   = (u16*)(arena + o_hb);
    u16*   avb  = (u16*)(arena + o_avb);
    u16*   midb = (u16*)(arena + o_midb);

    conv_all<<<53696, 256, 0, stream>>>(qkv_w, qkvT, res_w, resT,
                                        ff1_w, ff1T, ff2_w, ff2T, pred_w, predT,
                                        ids, bpe, pos, h, hb);

    for (int l = 0; l < NLAYER; ++l) {
        mfma_gemm<64, 256, 2, 0, 0, 1><<<dim3(MROWS / 64, 3 * HH / 128), 256, 0, stream>>>(
            hb, qkvT + (size_t)l * HH * 3 * HH, qkv_b + (size_t)l * 3 * HH,
            nullptr, qkvb, MROWS, 3 * HH, HH);
        attn_kernel<<<dim3(SS / 64, NHEAD, BB), 256, 0, stream>>>(qkvb, seq_mask, avb);
        mfma_gemm<32, 256, 2, 0, 0, 1><<<dim3(MROWS / 32, HH / 128), 256, 0, stream>>>(
            avb, resT + (size_t)l * HH * HH, res_b + (size_t)l * HH,
            nullptr, ab, MROWS, HH, HH);
        add_ln_kernel<<<MROWS / 4, 256, 0, stream>>>(h, hb, ab,
            ln1_g + (size_t)l * HH, ln1_b + (size_t)l * HH);
        mfma_gemm<64, 256, 2, 1, 0, 1><<<dim3(MROWS / 64, 4 * HH / 128), 256, 0, stream>>>(
            hb, ff1T + (size_t)l * HH * 4 * HH, ff1_b + (size_t)l * 4 * HH,
            nullptr, midb, MROWS, 4 * HH, HH);
        mfma_gemm<32, 256, 2, 0, 0, 1><<<dim3(MROWS / 32, HH / 128), 256, 0, stream>>>(
            midb, ff2T + (size_t)l * 4 * HH * HH, ff2_b + (size_t)l * HH,
            nullptr, ab, MROWS, HH, 4 * HH);
        add_ln_kernel<<<MROWS / 4, 256, 0, stream>>>(h, hb, ab,
            ln2_g + (size_t)l * HH, ln2_b + (size_t)l * HH);
    }

    mfma_gemm<128, 512, 4, 0, 1, 0><<<dim3(MROWS / 128, VV / 128), 512, 0, stream>>>(
        hb, predT, nullptr, out_score, nullptr, MROWS, VV, HH);
    softmax_v_kernel<<<MROWS, 512, 0, stream>>>(out_score, out_prob);
}